// Round 6
// baseline (545.574 us; speedup 1.0000x reference)
//
#include <hip/hip_runtime.h>
#include <hip/hip_bf16.h>

// Event-camera simulator: per-pixel independent scan over T frames.
// R6: 4 adjacent pixels per thread, all VMEM as dwordx4.
// Post-mortem R1/R2/R5: three different schedules (sunk loads / pinned /
// explicit asm burst) all measured ~127us, VALUBusy ~32%, VGPR 36-44 =>
// bottleneck is per-instruction vector-memory processing, not scheduling.
// R1-R5 issued 41 VMEM instrs per pixel (31 scalar rng dwords). This version
// issues ~17 per pixel: rng as one dwordx4 covering 4 pixels per t, frames
// as one dwordx4 per pixel per 4-t super-step (prefetched one step ahead),
// thresholds/states/out as dwordx4. Plain HIP, no inline asm.

namespace {
constexpr int Bc = 4, Hc = 480, Wc = 640, Tc = 32;
constexpr int HW   = Hc * Wc;       // 307200
constexpr int BHW  = Bc * HW;       // 1228800
constexpr int QHW  = HW / 4;        // 76800 threads per b
constexpr int NTHR = BHW / 4;       // 307200 threads total
}

typedef float v4 __attribute__((ext_vector_type(4)));

__device__ __forceinline__ float rfl(float x) {
    // wave-uniform value -> SGPR (b is block-uniform: 76800 % 256 == 0)
    return __uint_as_float(__builtin_amdgcn_readfirstlane(__float_as_uint(x)));
}

__global__ __launch_bounds__(256, 4) void event_sim_kernel(
    const float* __restrict__ log_images,    // (H, W, B*T)
    const float* __restrict__ image_ts,      // (B, T)
    const float* __restrict__ first_times,   // (B,)
    const float* __restrict__ thresholds,    // (2, B, H, W)
    const float* __restrict__ log_states,    // (B, H, W)
    const float* __restrict__ timestamps,    // (B, H, W)
    const float* __restrict__ prev_image_ts, // (B,)
    const float* __restrict__ refractory,    // (B,)
    const float* __restrict__ leak_rates,    // (B,)
    const float* __restrict__ shot_rates,    // (B,)
    const float* __restrict__ threshold_mus, // (B, 2)
    const float* __restrict__ rng,           // (T, B, H, W)
    float* __restrict__ out)                 // (B, H, W)
{
#pragma clang fp contract(off)
    const int tau = blockIdx.x * 256 + threadIdx.x;      // [0, NTHR)
    const int b   = tau / QHW;                           // block-uniform
    const int p4  = (tau - b * QHW) * 4;                 // first of 4 pixels
    const int base = b * HW + p4;                        // into (B,H,W) arrays

    // ---- per-b scalars (block-uniform -> SGPRs) ----
    const v4* ts4p = reinterpret_cast<const v4*>(image_ts) + b * (Tc / 4);
    float tss[Tc];
#pragma unroll
    for (int i = 0; i < Tc / 4; ++i) {
        v4 v = ts4p[i];
        tss[4*i+0] = rfl(v[0]); tss[4*i+1] = rfl(v[1]);
        tss[4*i+2] = rfl(v[2]); tss[4*i+3] = rfl(v[3]);
    }
    const float ref   = rfl(refractory[b]);
    const float leak  = rfl(leak_rates[b]);
    const float shot  = rfl(shot_rates[b]);
    const float mu_on = rfl(threshold_mus[2*b + 1]);
    const bool  ft    = rfl(first_times[b]) > 0.0f;
    const float pv    = rfl(prev_image_ts[b]);

    // ---- per-pixel dwordx4 loads ----
    const v4 thoff4 = *reinterpret_cast<const v4*>(thresholds + base);
    const v4 thon4  = *reinterpret_cast<const v4*>(thresholds + BHW + base);

    // frame chunk s=0 (t=0..3) for each of the 4 pixels
    // pixel P's 32 floats start at float index (P*4+b)*32
    v4 fc[4];
#pragma unroll
    for (int i = 0; i < 4; ++i)
        fc[i] = *reinterpret_cast<const v4*>(log_images + (p4 + i) * (4 * Tc) + b * Tc);

    float state[4], last[4], counts[4];
    float ts0;
    if (ft) {
        ts0 = tss[0];
#pragma unroll
        for (int i = 0; i < 4; ++i) {
            state[i] = fc[i][0];
            last[i]  = ts0 - ref;
        }
    } else {
        ts0 = pv;
        const v4 st4 = *reinterpret_cast<const v4*>(log_states + base);
        const v4 tm4 = *reinterpret_cast<const v4*>(timestamps + base);
#pragma unroll
        for (int i = 0; i < 4; ++i) { state[i] = st4[i]; last[i] = tm4[i]; }
    }
#pragma unroll
    for (int i = 0; i < 4; ++i) counts[i] = 0.0f;
    float ts_prev = ts0;

#pragma unroll
    for (int s = 0; s < 8; ++s) {
        // prefetch next frame chunk (independent of this step's compute)
        v4 fn[4];
        if (s < 7) {
#pragma unroll
            for (int i = 0; i < 4; ++i)
                fn[i] = *reinterpret_cast<const v4*>(
                    log_images + (p4 + i) * (4 * Tc) + b * Tc + 4 * (s + 1));
        }
        // rng planes for this chunk: one dwordx4 covers all 4 pixels
        v4 u4[4];
#pragma unroll
        for (int tt = 0; tt < 4; ++tt) {
            const int t = 4 * s + tt;
            if (t >= 1 && t < Tc)
                u4[tt] = *reinterpret_cast<const v4*>(rng + t * BHW + base);
        }
        // compute the 3 or 4 t-steps of this chunk, 4 pixels each
#pragma unroll
        for (int tt = 0; tt < 4; ++tt) {
            const int t = 4 * s + tt;
            if (t < 1) continue;
            const float ts_t = tss[t];
            const float dt   = ts_t - ts_prev;
            const float lk   = (leak * dt) * mu_on;
            const float psh  = shot * dt;
#pragma unroll
            for (int i = 0; i < 4; ++i) {
                float st = state[i] - lk;                  // reference association
                const float diff = fc[i][tt] - st;
                const bool  pos  = diff >= 0.0f;
                const float th   = pos ? thon4[i] : thoff4[i];
                float n = floorf(fabsf(diff) / th);        // IEEE div + exact floor
                const bool okb = (ts_t - last[i]) >= ref;
                n = okb ? n : 0.0f;
                const float pn = pos ? n : -n;             // pol * n
                st = st + (pn * th);                       // (pol*n)*th
                float cn = counts[i] + pn;
                float ls = (n > 0.0f) ? ts_t : last[i];

                const float u = u4[tt][i];
                const bool  is_shot = (u < psh) && ((ts_t - ls) >= ref);
                const float pol_s   = (u < (0.5f * psh)) ? 1.0f : -1.0f;
                cn = is_shot ? (cn + pol_s) : cn;
                ls = is_shot ? ts_t : ls;

                state[i] = st; counts[i] = cn; last[i] = ls;
            }
            ts_prev = ts_t;
        }
        if (s < 7) {
#pragma unroll
            for (int i = 0; i < 4; ++i) fc[i] = fn[i];
        }
    }

    v4 o;
#pragma unroll
    for (int i = 0; i < 4; ++i) o[i] = counts[i];
    *reinterpret_cast<v4*>(out + base) = o;
}

extern "C" void kernel_launch(void* const* d_in, const int* in_sizes, int n_in,
                              void* d_out, int out_size, void* d_ws, size_t ws_size,
                              hipStream_t stream) {
    const float* log_images    = (const float*)d_in[0];
    // d_in[1] = video_len (int64) — unused by the reference computation
    const float* image_ts      = (const float*)d_in[2];
    const float* first_times   = (const float*)d_in[3];
    const float* thresholds    = (const float*)d_in[4];
    const float* log_states    = (const float*)d_in[5];
    const float* timestamps    = (const float*)d_in[6];
    const float* prev_image_ts = (const float*)d_in[7];
    const float* refractory    = (const float*)d_in[8];
    const float* leak_rates    = (const float*)d_in[9];
    const float* shot_rates    = (const float*)d_in[10];
    const float* threshold_mus = (const float*)d_in[11];
    const float* rng           = (const float*)d_in[12];
    float* out = (float*)d_out;

    dim3 grid(NTHR / 256);   // 1200 blocks
    dim3 block(256);
    hipLaunchKernelGGL(event_sim_kernel, grid, block, 0, stream,
                       log_images, image_ts, first_times, thresholds,
                       log_states, timestamps, prev_image_ts, refractory,
                       leak_rates, shot_rates, threshold_mus, rng, out);
}